// Round 8
// baseline (511.746 us; speedup 1.0000x reference)
//
#include <hip/hip_runtime.h>

// 2-layer LSTM (HID=10), B=2048, T=1024 main + F=64 future steps.
// One element per wave, 2048 single-wave blocks = 2 waves/SIMD on all 1024 SIMDs.
// Lane L = k*10+u owns gate row L; cells software-pipelined (cell1(t+1) || cell2(t)).
//
// Round 8: h-broadcast via LDS round trip. r7 showed packed fp32 can't help
// (scalar v_fma already saturates the fp32 pipe: 157.3TF = 32768 lanes*2*2.4G)
// and VALU-busy is the binding pipe (645/896 cyc/SIMD/step). The ~250 cyc of
// non-dot VALU overhead was broadcasts+marshaling: 10 bperm + insert movs per h.
// Now: lanes 0..9 ds_write_b32 h_u; all lanes re-read as 3 wave-uniform loads
// (b128+b128+b64) straight into the VGPR quads the dot fmas consume. 4 DS ops
// per h, zero movs. Gathers (f/g/o) stay 3 bperm per cell. All scalar math.

#define NB 2048
#define TMAIN 1024
#define HID 10

#define PIN(v)  asm volatile("" : "+v"(v))

__device__ __forceinline__ float rcp_(float v)  { return __builtin_amdgcn_rcpf(v); }
__device__ __forceinline__ float exp2_(float v) { return __builtin_amdgcn_exp2f(v); }

__global__ __launch_bounds__(64)
__attribute__((amdgpu_waves_per_eu(2, 2)))
void lstm2_kernel(
    const float* __restrict__ x,
    const float* __restrict__ Wih1, const float* __restrict__ Whh1,
    const float* __restrict__ bih1, const float* __restrict__ bhh1,
    const float* __restrict__ Wih2, const float* __restrict__ Whh2,
    const float* __restrict__ bih2, const float* __restrict__ bhh2,
    const float* __restrict__ Wlin, const float* __restrict__ blin,
    const int* __restrict__ futp,
    float* __restrict__ out)
{
    // LDS: h1 at [0..9], dump at [16..25] (k>0 lanes), h2 at [32..41]
    __shared__ __align__(16) float hb[48];

    const int lane = threadIdx.x;
    const int ge   = blockIdx.x;
    const int F    = futp[0];
    const int OUTW = TMAIN + F;

    const int L = (lane < 40) ? lane : 0;   // shadows mirror lane 0 exactly
    const int k = L / HID;
    const int u = L - k * HID;

    const bool isg = (k == 2);
    const float aK = isg ?  2.8853900817779268f : -1.4426950408889634f;
    const float tK = 2.8853900817779268f;
    const float aA = isg ?  tK        : 0.0f;   // g-gate act pre-scaled by tK
    const float aB = isg ? -2.0f * tK : 1.0f;   // so cell state carries tK*c

    // write slots: real h for k==0 lanes (shadows carry identical values), dump else
    const int a1 = k ? (16 + u) : u;
    const int a2 = k ? (16 + u) : (32 + u);

    // ---- per-lane weights (row L), prescaled by aK ----
    float whh1v[HID], wih2v[HID], whh2v[HID], wlinv[HID];
    #pragma unroll
    for (int j = 0; j < HID; ++j) {
        whh1v[j] = Whh1[L * HID + j] * aK;
        wih2v[j] = Wih2[L * HID + j] * aK;
        whh2v[j] = Whh2[L * HID + j] * aK;
        wlinv[j] = Wlin[j];
    }
    float wih1v = Wih1[L] * aK;
    float b1 = (bih1[L] + bhh1[L]) * aK;
    float b2 = (bih2[L] + bhh2[L]) * aK;
    float bl = blin[0];

    #pragma unroll
    for (int j = 0; j < HID; ++j) { PIN(whh1v[j]); PIN(wih2v[j]); PIN(whh2v[j]); PIN(wlinv[j]); }
    PIN(wih1v); PIN(b1); PIN(b2); PIN(bl);

    const int adr_f = (1 * HID + u) * 4;
    const int adr_g = (2 * HID + u) * 4;
    const int adr_o = (3 * HID + u) * 4;

    auto bp = [](int addr, float v) -> float {
        return __int_as_float(__builtin_amdgcn_ds_bpermute(addr, __float_as_int(v)));
    };
    auto actf = [&](float p) -> float {          // sigma (or tK*tanh on g-lanes)
        return fmaf(aB, rcp_(1.0f + exp2_(p)), aA);
    };
    auto ctanh = [&](float cs) -> float {        // tanh of (pre-scaled) cell state
        return fmaf(-2.0f, rcp_(1.0f + exp2_(cs)), 1.0f);
    };

    // ---- state: c on lanes 0..9 (scaled); h replicated in float4/float2 regs ----
    float c1 = 0.f, c2 = 0.f;
    float4 h1A = make_float4(0.f,0.f,0.f,0.f), h1B = h1A, h2A = h1A, h2B = h1A;
    float2 h1C = make_float2(0.f,0.f),          h2C = h1C;

    auto bcast1 = [&](float h1u) {
        hb[a1] = h1u;
        h1A = *(const float4*)&hb[0];
        h1B = *(const float4*)&hb[4];
        h1C = *(const float2*)&hb[8];
    };
    auto bcast2 = [&](float h2u) {
        hb[a2] = h2u;
        h2A = *(const float4*)&hb[32];
        h2B = *(const float4*)&hb[36];
        h2C = *(const float2*)&hb[40];
    };
    auto head = [&]() -> float {
        float y0 = fmaf(h2A.x, wlinv[0], bl);
        float y1 = h2B.y * wlinv[5];
        y0 = fmaf(h2A.y, wlinv[1], y0);  y1 = fmaf(h2B.z, wlinv[6], y1);
        y0 = fmaf(h2A.z, wlinv[2], y0);  y1 = fmaf(h2B.w, wlinv[7], y1);
        y0 = fmaf(h2A.w, wlinv[3], y0);  y1 = fmaf(h2C.x, wlinv[8], y1);
        y0 = fmaf(h2B.x, wlinv[4], y0);  y1 = fmaf(h2C.y, wlinv[9], y1);
        return y0 + y1;
    };

    // Pipelined iteration t: cell2(t) and cell1(t+1) as parallel chains.
    auto pipe_iter = [&](float xnext) -> float {
        // cell2 pre-act: 4 chains of 5
        float u0 = fmaf(h1A.x, wih2v[0], b2);
        float u1 = h1B.y * wih2v[5];
        float v0 = h2A.x * whh2v[0];
        float v1 = h2B.y * whh2v[5];
        u0 = fmaf(h1A.y, wih2v[1], u0);  u1 = fmaf(h1B.z, wih2v[6], u1);
        v0 = fmaf(h2A.y, whh2v[1], v0);  v1 = fmaf(h2B.z, whh2v[6], v1);
        u0 = fmaf(h1A.z, wih2v[2], u0);  u1 = fmaf(h1B.w, wih2v[7], u1);
        v0 = fmaf(h2A.z, whh2v[2], v0);  v1 = fmaf(h2B.w, whh2v[7], v1);
        u0 = fmaf(h1A.w, wih2v[3], u0);  u1 = fmaf(h1C.x, wih2v[8], u1);
        v0 = fmaf(h2A.w, whh2v[3], v0);  v1 = fmaf(h2C.x, whh2v[8], v1);
        u0 = fmaf(h1B.x, wih2v[4], u0);  u1 = fmaf(h1C.y, wih2v[9], u1);
        v0 = fmaf(h2B.x, whh2v[4], v0);  v1 = fmaf(h2C.y, whh2v[9], v1);
        float d = (u0 + u1) + (v0 + v1);
        // cell1(t+1) pre-act: 2 chains of 5(+x)
        float p0 = fmaf(xnext, wih1v, b1);
        float p1 = h1B.y * whh1v[5];
        p0 = fmaf(h1A.x, whh1v[0], p0);  p1 = fmaf(h1B.z, whh1v[6], p1);
        p0 = fmaf(h1A.y, whh1v[1], p0);  p1 = fmaf(h1B.w, whh1v[7], p1);
        p0 = fmaf(h1A.z, whh1v[2], p0);  p1 = fmaf(h1C.x, whh1v[8], p1);
        p0 = fmaf(h1A.w, whh1v[3], p0);  p1 = fmaf(h1C.y, whh1v[9], p1);
        p0 = fmaf(h1B.x, whh1v[4], p0);
        float a = p0 + p1;
        // activations
        float act2 = actf(d);
        float act1 = actf(a);
        // gathers (6 independent bperm)
        float f2 = bp(adr_f, act2), g2 = bp(adr_g, act2), o2 = bp(adr_o, act2);
        float f1 = bp(adr_f, act1), g1 = bp(adr_g, act1), o1 = bp(adr_o, act1);
        // c updates (real on lanes 0..9 and shadows; act == i-gate there)
        c2 = fmaf(f2, c2, act2 * g2);
        c1 = fmaf(f1, c1, act1 * g1);
        float h2u = o2 * ctanh(c2);
        float h1u = o1 * ctanh(c1);
        // broadcast via LDS: 2 writes then 6 uniform reads
        hb[a1] = h1u;
        hb[a2] = h2u;
        h1A = *(const float4*)&hb[0];
        h1B = *(const float4*)&hb[4];
        h1C = *(const float2*)&hb[8];
        h2A = *(const float4*)&hb[32];
        h2B = *(const float4*)&hb[36];
        h2C = *(const float2*)&hb[40];
        return head();
    };

    auto cell2_only = [&]() -> float {
        float u0 = fmaf(h1A.x, wih2v[0], b2);
        float u1 = h1B.y * wih2v[5];
        float v0 = h2A.x * whh2v[0];
        float v1 = h2B.y * whh2v[5];
        u0 = fmaf(h1A.y, wih2v[1], u0);  u1 = fmaf(h1B.z, wih2v[6], u1);
        v0 = fmaf(h2A.y, whh2v[1], v0);  v1 = fmaf(h2B.z, whh2v[6], v1);
        u0 = fmaf(h1A.z, wih2v[2], u0);  u1 = fmaf(h1B.w, wih2v[7], u1);
        v0 = fmaf(h2A.z, whh2v[2], v0);  v1 = fmaf(h2B.w, whh2v[7], v1);
        u0 = fmaf(h1A.w, wih2v[3], u0);  u1 = fmaf(h1C.x, wih2v[8], u1);
        v0 = fmaf(h2A.w, whh2v[3], v0);  v1 = fmaf(h2C.x, whh2v[8], v1);
        u0 = fmaf(h1B.x, wih2v[4], u0);  u1 = fmaf(h1C.y, wih2v[9], u1);
        v0 = fmaf(h2B.x, whh2v[4], v0);  v1 = fmaf(h2C.y, whh2v[9], v1);
        float act2 = actf((u0 + u1) + (v0 + v1));
        float f2 = bp(adr_f, act2), g2 = bp(adr_g, act2), o2 = bp(adr_o, act2);
        c2 = fmaf(f2, c2, act2 * g2);
        float h2u = o2 * ctanh(c2);
        bcast2(h2u);
        return head();
    };

    auto fstep = [&](float xt) -> float {        // serial step for future loop
        float p0 = fmaf(xt, wih1v, b1);
        float p1 = h1B.y * whh1v[5];
        p0 = fmaf(h1A.x, whh1v[0], p0);  p1 = fmaf(h1B.z, whh1v[6], p1);
        p0 = fmaf(h1A.y, whh1v[1], p0);  p1 = fmaf(h1B.w, whh1v[7], p1);
        p0 = fmaf(h1A.z, whh1v[2], p0);  p1 = fmaf(h1C.x, whh1v[8], p1);
        p0 = fmaf(h1A.w, whh1v[3], p0);  p1 = fmaf(h1C.y, whh1v[9], p1);
        p0 = fmaf(h1B.x, whh1v[4], p0);
        float act1 = actf(p0 + p1);
        float f1 = bp(adr_f, act1), g1 = bp(adr_g, act1), o1 = bp(adr_o, act1);
        c1 = fmaf(f1, c1, act1 * g1);
        float h1u = o1 * ctanh(c1);
        bcast1(h1u);
        return cell2_only();
    };

    // ---- prologue: h1(0), c1(0) from x[0] (h1 == 0) ----
    const float4* xrow = (const float4*)(x + (size_t)ge * TMAIN);
    float4* orow = (float4*)(out + (size_t)ge * OUTW);   // OUTW=1088, 16B-aligned
    float4 xv = xrow[0];
    {
        float act1 = actf(fmaf(xv.x, wih1v, b1));
        float g1 = bp(adr_g, act1), o1 = bp(adr_o, act1);
        c1 = act1 * g1;                                   // c1_old == 0
        float h1u = o1 * ctanh(c1);
        bcast1(h1u);
    }

    // ---- main loop: 255 groups of 4 pipelined iterations ----
    #pragma unroll 1
    for (int t4 = 0; t4 < TMAIN / 4 - 1; ++t4) {
        float4 xn = xrow[t4 + 1];
        float y0 = pipe_iter(xv.y);
        float y1 = pipe_iter(xv.z);
        float y2 = pipe_iter(xv.w);
        float y3 = pipe_iter(xn.x);
        if (lane == 0) orow[t4] = make_float4(y0, y1, y2, y3);
        xv = xn;
    }
    {
        float y0 = pipe_iter(xv.y);
        float y1 = pipe_iter(xv.z);
        float y2 = pipe_iter(xv.w);
        float y3 = cell2_only();
        if (lane == 0) orow[TMAIN / 4 - 1] = make_float4(y0, y1, y2, y3);
    }

    // ---- future loop: serial (y feeds back; y uniform on all lanes) ----
    float yprev = head();
    int t = 0;
    #pragma unroll 1
    for (; t + 3 < F; t += 4) {
        float y0 = fstep(yprev);
        float y1 = fstep(y0);
        float y2 = fstep(y1);
        float y3 = fstep(y2);
        if (lane == 0) orow[(TMAIN + t) / 4] = make_float4(y0, y1, y2, y3);
        yprev = y3;
    }
    #pragma unroll 1
    for (; t < F; ++t) {
        yprev = fstep(yprev);
        if (lane == 0) out[(size_t)ge * OUTW + TMAIN + t] = yprev;
    }
}

extern "C" void kernel_launch(void* const* d_in, const int* in_sizes, int n_in,
                              void* d_out, int out_size, void* d_ws, size_t ws_size,
                              hipStream_t stream) {
    const float* x    = (const float*)d_in[0];
    const float* Wih1 = (const float*)d_in[1];
    const float* Whh1 = (const float*)d_in[2];
    const float* bih1 = (const float*)d_in[3];
    const float* bhh1 = (const float*)d_in[4];
    const float* Wih2 = (const float*)d_in[5];
    const float* Whh2 = (const float*)d_in[6];
    const float* bih2 = (const float*)d_in[7];
    const float* bhh2 = (const float*)d_in[8];
    const float* Wlin = (const float*)d_in[9];
    const float* blin = (const float*)d_in[10];
    const int*   futp = (const int*)d_in[11];
    float* out = (float*)d_out;

    lstm2_kernel<<<NB, 64, 0, stream>>>(x, Wih1, Whh1, bih1, bhh1,
                                        Wih2, Whh2, bih2, bhh2,
                                        Wlin, blin, futp, out);
}